// Round 1
// baseline (88.780 us; speedup 1.0000x reference)
//
#include <hip/hip_runtime.h>
#include <math.h>

#define IMG_H 240
#define IMG_W 320
#define NG 512
#define NEAR_P 0.1f
#define FAR_P 100.0f

// kernel 2 geometry: 16x8 tiles, 1 thread per pixel
#define TILE_W 16
#define TILE_H 8
#define TPB2 128

struct GP {
    float px, py, ia, ib, ic, op, cr, cg, cb, z, xlo, xhi, ylo, yhi, radius;
    int vis;
};

__device__ __forceinline__ float fast_rcp(float x) { return __builtin_amdgcn_rcpf(x); }
__device__ __forceinline__ float fast_rsq(float x) { return __builtin_amdgcn_rsqf(x); }

__device__ __forceinline__ GP prep_gaussian(
    int i,
    const float* __restrict__ means, const float* __restrict__ scales,
    const float* __restrict__ rots,  const float* __restrict__ colors,
    const float* __restrict__ opac,
    float fx, float fy, float cx, float cy,
    float Rc00, float Rc01, float Rc02, float t0,
    float Rc10, float Rc11, float Rc12, float t1,
    float Rc20, float Rc21, float Rc22, float t2)
{
    GP g;

    const float mx = means[3*i+0], my = means[3*i+1], mz = means[3*i+2];
    const float xc = Rc00*mx + Rc01*my + Rc02*mz + t0;
    const float yc = Rc10*mx + Rc11*my + Rc12*mz + t1;
    const float zc = Rc20*mx + Rc21*my + Rc22*mz + t2;

    const float zs = (zc == 0.0f) ? 1e-8f : zc;
    const float iz = fast_rcp(zs);
    const float px = fx * xc * iz + cx;
    const float py = fy * yc * iz + cy;

    // quaternion -> rotmat (rsq-normalized)
    float qw = rots[4*i+0], qx = rots[4*i+1], qy = rots[4*i+2], qz = rots[4*i+3];
    const float iqn = fast_rsq(qw*qw + qx*qx + qy*qy + qz*qz);
    qw *= iqn; qx *= iqn; qy *= iqn; qz *= iqn;
    float R[3][3];
    R[0][0] = 1.0f - 2.0f*(qy*qy + qz*qz);
    R[0][1] = 2.0f*(qx*qy - qw*qz);
    R[0][2] = 2.0f*(qx*qz + qw*qy);
    R[1][0] = 2.0f*(qx*qy + qw*qz);
    R[1][1] = 1.0f - 2.0f*(qx*qx + qz*qz);
    R[1][2] = 2.0f*(qy*qz - qw*qx);
    R[2][0] = 2.0f*(qx*qz - qw*qy);
    R[2][1] = 2.0f*(qy*qz + qw*qx);
    R[2][2] = 1.0f - 2.0f*(qx*qx + qy*qy);

    const float s0 = scales[3*i+0], s1 = scales[3*i+1], s2v = scales[3*i+2];
    const float ss[3] = { s0*s0, s1*s1, s2v*s2v };

    // cov3d M = R diag(ss) R^T
    float M3[3][3];
    #pragma unroll
    for (int r = 0; r < 3; ++r)
        #pragma unroll
        for (int c = 0; c < 3; ++c)
            M3[r][c] = R[r][0]*ss[0]*R[c][0] + R[r][1]*ss[1]*R[c][1] + R[r][2]*ss[2]*R[c][2];

    // V = Rc M Rc^T
    const float Rcm[3][3] = {{Rc00,Rc01,Rc02},{Rc10,Rc11,Rc12},{Rc20,Rc21,Rc22}};
    float A[3][3];
    #pragma unroll
    for (int r = 0; r < 3; ++r)
        #pragma unroll
        for (int c = 0; c < 3; ++c)
            A[r][c] = Rcm[r][0]*M3[0][c] + Rcm[r][1]*M3[1][c] + Rcm[r][2]*M3[2][c];
    float V[3][3];
    #pragma unroll
    for (int r = 0; r < 3; ++r)
        #pragma unroll
        for (int c = 0; c < 3; ++c)
            V[r][c] = A[r][0]*Rcm[c][0] + A[r][1]*Rcm[c][1] + A[r][2]*Rcm[c][2];

    const float j00 = fx * iz, j02 = -fx * xc * iz * iz;
    const float j11 = fy * iz, j12 = -fy * yc * iz * iz;
    float P0[3], P1[3];
    #pragma unroll
    for (int c = 0; c < 3; ++c) {
        P0[c] = j00*V[0][c] + j02*V[2][c];
        P1[c] = j11*V[1][c] + j12*V[2][c];
    }
    const float a = P0[0]*j00 + P0[2]*j02;
    const float b = P0[1]*j11 + P0[2]*j12;
    const float c = P1[1]*j11 + P1[2]*j12;

    const float lam_max = 0.5f*(a + c) + sqrtf(fmaxf(0.25f*(a - c)*(a - c) + b*b, 0.0f));
    const float radius = 3.0f * sqrtf(fmaxf(lam_max, 0.0f));

    const bool visible = (zc > NEAR_P) && (zc < FAR_P) &&
                         (px >= 0.0f) && (px < (float)IMG_W) &&
                         (py >= 0.0f) && (py < (float)IMG_H);

    const float eps = 1e-6f;
    const float ae = a + eps, ce = c + eps;
    const float det = ae*ce - b*b;
    const float idet = fast_rcp(det);

    g.px = px; g.py = py;
    g.ia = ce * idet; g.ib = -b * idet; g.ic = ae * idet;
    g.op = opac[i];
    g.cr = colors[3*i+0]; g.cg = colors[3*i+1]; g.cb = colors[3*i+2];
    g.z = zc;
    const float cxp = floorf(px), cyp = floorf(py);
    const float r_int = floorf(radius) + 1.0f;
    g.xlo = cxp - r_int; g.xhi = cxp + r_int;
    g.ylo = cyp - r_int; g.yhi = cyp + r_int;
    g.vis = visible ? 1 : 0;
    g.radius = radius;
    return g;
}

// ---------------- kernel 1: prep + global stable z-sort (runs ONCE) ----------------
// 1 block x 512 threads. Writes to workspace, in globally z-sorted order:
//   ws[0..NG)        : float4 box  = {xlo, xhi, ylo, yhi}  (sentinel for invisible)
//   ws[NG..NG+3*NG)  : float4 rows = {px,py,ia,ib} {ic,op,z,cr} {cg,cb,-,-}
// Also writes radii to out (original gaussian order).
__global__ void __launch_bounds__(512)
prep_sort_kernel(const float* __restrict__ means,
                 const float* __restrict__ scales,
                 const float* __restrict__ rots,
                 const float* __restrict__ colors,
                 const float* __restrict__ opac,
                 const float* __restrict__ Km,
                 const float* __restrict__ Tm,
                 float4* __restrict__ ws,
                 float* __restrict__ out)
{
    __shared__ float s_zkey[NG];

    const int i = threadIdx.x;   // one gaussian per thread

    const float fx = Km[0], fy = Km[4], cx = Km[2], cy = Km[5];
    const float Rc00 = Tm[0],  Rc01 = Tm[1],  Rc02 = Tm[2],  t0 = Tm[3];
    const float Rc10 = Tm[4],  Rc11 = Tm[5],  Rc12 = Tm[6],  t1 = Tm[7];
    const float Rc20 = Tm[8],  Rc21 = Tm[9],  Rc22 = Tm[10], t2 = Tm[11];

    GP p = prep_gaussian(i, means, scales, rots, colors, opac, fx, fy, cx, cy,
                         Rc00, Rc01, Rc02, t0, Rc10, Rc11, Rc12, t1, Rc20, Rc21, Rc22, t2);

    // radii output (original order)
    out[IMG_H*IMG_W*5 + i] = p.vis ? p.radius : 0.0f;

    // stable rank by descending key (matches jnp.argsort(-key), stable)
    const float key = p.vis ? p.z : -1e30f;
    s_zkey[i] = key;
    __syncthreads();

    int r = 0;
    for (int j = 0; j < NG; ++j) {
        const float kj = s_zkey[j];
        r += (kj > key) || (kj == key && j < i);
    }

    float4* boxes = ws;
    float4* rows  = ws + NG;
    // sentinel box for invisible -> tile cull always fails, never enters composite
    boxes[r] = p.vis ? make_float4(p.xlo, p.xhi, p.ylo, p.yhi)
                     : make_float4(1e30f, -1e30f, 1e30f, -1e30f);
    rows[3*r+0] = make_float4(p.px, p.py, p.ia, p.ib);
    rows[3*r+1] = make_float4(p.ic, p.op, p.z,  p.cr);
    rows[3*r+2] = make_float4(p.cg, p.cb, 0.0f, 0.0f);
}

// ---------------- kernel 2: per-tile cull + stable compact (pre-sorted) + composite ----------------
// 16x8 tiles, 128 threads (2 waves), 600 blocks. Stable compaction of the
// globally z-sorted list IS the per-tile sort — no rank pass needed.
__global__ void __launch_bounds__(TPB2)
tile_render_kernel(const float4* __restrict__ ws,
                   float* __restrict__ out)
{
    __shared__ float4 s_g[NG * 4 + 4];   // +4: prefetch overread pad
    __shared__ int    s_wsum[2];

    const int tid  = threadIdx.x;
    const int lane = tid & 63;
    const int wid  = tid >> 6;

    const int tiles_x = IMG_W / TILE_W;              // 20
    const int tile_id = blockIdx.x;
    const int tx0 = (tile_id % tiles_x) * TILE_W;
    const int ty0 = (tile_id / tiles_x) * TILE_H;
    const float ftx0 = (float)tx0, ftx1 = (float)(tx0 + TILE_W - 1);
    const float fty0 = (float)ty0, fty1 = (float)(ty0 + TILE_H - 1);

    const float4* __restrict__ boxes = ws;
    const float4* __restrict__ rows  = ws + NG;

    // --- cull 4 pre-sorted gaussians per thread (64B coalesced load) ---
    const int base = 4 * tid;
    float4 b0 = boxes[base+0];
    float4 b1 = boxes[base+1];
    float4 b2 = boxes[base+2];
    float4 b3 = boxes[base+3];
    const int f0 = (b0.y >= ftx0) && (b0.x <= ftx1) && (b0.w >= fty0) && (b0.z <= fty1);
    const int f1 = (b1.y >= ftx0) && (b1.x <= ftx1) && (b1.w >= fty0) && (b1.z <= fty1);
    const int f2 = (b2.y >= ftx0) && (b2.x <= ftx1) && (b2.w >= fty0) && (b2.z <= fty1);
    const int f3 = (b3.y >= ftx0) && (b3.x <= ftx1) && (b3.w >= fty0) && (b3.z <= fty1);
    const int cnt = f0 + f1 + f2 + f3;

    // --- stable prefix scan (wave shuffle + cross-wave offset) ---
    int c = cnt;
    #pragma unroll
    for (int d = 1; d < 64; d <<= 1) {
        int n = __shfl_up(c, d);
        if (lane >= d) c += n;
    }
    if (lane == 63) s_wsum[wid] = c;
    __syncthreads();
    const int woff = (wid == 1) ? s_wsum[0] : 0;
    const int M    = s_wsum[0] + s_wsum[1];
    int q = woff + c - cnt;    // exclusive position; order == sorted order

    // --- write survivors' AoS rows into LDS at compact (z-sorted) slots ---
    if (f0) { s_g[4*q+0]=b0; s_g[4*q+1]=rows[3*(base+0)+0]; s_g[4*q+2]=rows[3*(base+0)+1]; s_g[4*q+3]=rows[3*(base+0)+2]; ++q; }
    if (f1) { s_g[4*q+0]=b1; s_g[4*q+1]=rows[3*(base+1)+0]; s_g[4*q+2]=rows[3*(base+1)+1]; s_g[4*q+3]=rows[3*(base+1)+2]; ++q; }
    if (f2) { s_g[4*q+0]=b2; s_g[4*q+1]=rows[3*(base+2)+0]; s_g[4*q+2]=rows[3*(base+2)+1]; s_g[4*q+3]=rows[3*(base+2)+2]; ++q; }
    if (f3) { s_g[4*q+0]=b3; s_g[4*q+1]=rows[3*(base+3)+0]; s_g[4*q+2]=rows[3*(base+3)+1]; s_g[4*q+3]=rows[3*(base+3)+2]; ++q; }
    __syncthreads();

    // --- composite: one thread per pixel, 1-deep LDS box prefetch ---
    const int lx = tid & (TILE_W - 1);
    const int ly = tid >> 4;
    const int xi = tx0 + lx;
    const int yi = ty0 + ly;
    const float gx = (float)xi;
    const float gy = (float)yi;

    float T = 1.0f;
    float accR = 0.0f, accG = 0.0f, accB = 0.0f, accA = 0.0f;
    float depth = 0.0f;
    bool has = false;

    float4 box = s_g[0];
    for (int i = 0; i < M; ++i) {
        const float4 boxn = s_g[4*i+4];   // prefetch next (pad makes i==M-1 safe)
        if (gx >= box.x && gx <= box.y && gy >= box.z && gy <= box.w) {
            const float4 r1 = s_g[4*i+1];
            const float4 r2 = s_g[4*i+2];
            const float4 r3 = s_g[4*i+3];
            const float dx = gx - r1.x;
            const float dy = gy - r1.y;
            const float mahal = r1.z*dx*dx + 2.0f*r1.w*dx*dy + r2.x*dy*dy;
            const float g = __expf(-0.5f * mahal);
            const float alpha = fminf(r2.y * g, 0.99f);   // op*g >= 0 always
            const float w = alpha * T;
            accR += w * r2.w;
            accG += w * r3.x;
            accB += w * r3.y;
            accA += w;
            if (!has && w > 0.01f) { depth = r2.z; has = true; }
            T *= (1.0f - alpha);
            // future contributions bounded by T: color/alpha error <= 1e-4,
            // and future w < 1e-4 < 0.01 can never set depth -> safe early out.
            if (T < 1e-4f) break;
        }
        box = boxn;
    }

    const int p = yi * IMG_W + xi;
    float* rendered  = out;                          // [H,W,3]
    float* depth_map = out + IMG_H*IMG_W*3;          // [H,W]
    float* alpha_map = out + IMG_H*IMG_W*4;          // [H,W]

    rendered[3*p+0] = fminf(fmaxf(accR, 0.0f), 1.0f);
    rendered[3*p+1] = fminf(fmaxf(accG, 0.0f), 1.0f);
    rendered[3*p+2] = fminf(fmaxf(accB, 0.0f), 1.0f);
    depth_map[p] = has ? depth : 0.0f;
    alpha_map[p] = fminf(fmaxf(accA, 0.0f), 1.0f);
}

extern "C" void kernel_launch(void* const* d_in, const int* in_sizes, int n_in,
                              void* d_out, int out_size, void* d_ws, size_t ws_size,
                              hipStream_t stream) {
    const float* means  = (const float*)d_in[0];
    const float* scales = (const float*)d_in[1];
    const float* rots   = (const float*)d_in[2];
    const float* colors = (const float*)d_in[3];
    const float* opac   = (const float*)d_in[4];
    const float* Km     = (const float*)d_in[5];
    const float* Tm     = (const float*)d_in[6];
    float* out = (float*)d_out;
    float4* ws4 = (float4*)d_ws;
    (void)in_sizes; (void)n_in; (void)out_size; (void)ws_size;

    // kernel 1: prep + global stable z-sort (one block, runs once)
    hipLaunchKernelGGL(prep_sort_kernel, dim3(1), dim3(NG), 0, stream,
                       means, scales, rots, colors, opac, Km, Tm, ws4, out);

    // kernel 2: per-tile render, 16x8 tiles
    const int ntiles = (IMG_W / TILE_W) * (IMG_H / TILE_H);   // 600
    hipLaunchKernelGGL(tile_render_kernel, dim3(ntiles), dim3(TPB2), 0, stream,
                       (const float4*)d_ws, out);
}

// Round 2
// 77.040 us; speedup vs baseline: 1.1524x; 1.1524x over previous
//
#include <hip/hip_runtime.h>
#include <math.h>

#define IMG_H 240
#define IMG_W 320
#define NG 512
#define NEAR_P 0.1f
#define FAR_P 100.0f

// 16x20 tiles -> 20x12 = 240 blocks: one block per CU (256 CUs), no 2x makespan
// quantization (vs 300 blocks where 44 CUs ran two tiles serially).
#define TILE_W 16
#define TILE_H 20
#define TPB 320                 // 5 waves; one thread per pixel of the 16x20 tile

struct GP {
    float px, py, ia, ib, ic, op, cr, cg, cb, z, xlo, xhi, ylo, yhi, radius;
    int vis;
};

__device__ __forceinline__ float fast_rcp(float x) { return __builtin_amdgcn_rcpf(x); }
__device__ __forceinline__ float fast_rsq(float x) { return __builtin_amdgcn_rsqf(x); }

__device__ __forceinline__ GP prep_gaussian(
    int i,
    const float* __restrict__ means, const float* __restrict__ scales,
    const float* __restrict__ rots,  const float* __restrict__ colors,
    const float* __restrict__ opac,
    float fx, float fy, float cx, float cy,
    float Rc00, float Rc01, float Rc02, float t0,
    float Rc10, float Rc11, float Rc12, float t1,
    float Rc20, float Rc21, float Rc22, float t2)
{
    GP g;

    const float mx = means[3*i+0], my = means[3*i+1], mz = means[3*i+2];
    const float xc = Rc00*mx + Rc01*my + Rc02*mz + t0;
    const float yc = Rc10*mx + Rc11*my + Rc12*mz + t1;
    const float zc = Rc20*mx + Rc21*my + Rc22*mz + t2;

    const float zs = (zc == 0.0f) ? 1e-8f : zc;
    const float iz = fast_rcp(zs);
    const float px = fx * xc * iz + cx;
    const float py = fy * yc * iz + cy;

    // quaternion -> rotmat (rsq-normalized); rots is float4-aligned
    const float4 q4 = ((const float4*)rots)[i];
    float qw = q4.x, qx = q4.y, qy = q4.z, qz = q4.w;
    const float iqn = fast_rsq(qw*qw + qx*qx + qy*qy + qz*qz);
    qw *= iqn; qx *= iqn; qy *= iqn; qz *= iqn;
    float R[3][3];
    R[0][0] = 1.0f - 2.0f*(qy*qy + qz*qz);
    R[0][1] = 2.0f*(qx*qy - qw*qz);
    R[0][2] = 2.0f*(qx*qz + qw*qy);
    R[1][0] = 2.0f*(qx*qy + qw*qz);
    R[1][1] = 1.0f - 2.0f*(qx*qx + qz*qz);
    R[1][2] = 2.0f*(qy*qz - qw*qx);
    R[2][0] = 2.0f*(qx*qz - qw*qy);
    R[2][1] = 2.0f*(qy*qz + qw*qx);
    R[2][2] = 1.0f - 2.0f*(qx*qx + qy*qy);

    const float s0 = scales[3*i+0], s1 = scales[3*i+1], s2v = scales[3*i+2];
    const float ss[3] = { s0*s0, s1*s1, s2v*s2v };

    // cov3d M = R diag(ss) R^T
    float M3[3][3];
    #pragma unroll
    for (int r = 0; r < 3; ++r)
        #pragma unroll
        for (int c = 0; c < 3; ++c)
            M3[r][c] = R[r][0]*ss[0]*R[c][0] + R[r][1]*ss[1]*R[c][1] + R[r][2]*ss[2]*R[c][2];

    // V = Rc M Rc^T
    const float Rcm[3][3] = {{Rc00,Rc01,Rc02},{Rc10,Rc11,Rc12},{Rc20,Rc21,Rc22}};
    float A[3][3];
    #pragma unroll
    for (int r = 0; r < 3; ++r)
        #pragma unroll
        for (int c = 0; c < 3; ++c)
            A[r][c] = Rcm[r][0]*M3[0][c] + Rcm[r][1]*M3[1][c] + Rcm[r][2]*M3[2][c];
    float V[3][3];
    #pragma unroll
    for (int r = 0; r < 3; ++r)
        #pragma unroll
        for (int c = 0; c < 3; ++c)
            V[r][c] = A[r][0]*Rcm[c][0] + A[r][1]*Rcm[c][1] + A[r][2]*Rcm[c][2];

    const float j00 = fx * iz, j02 = -fx * xc * iz * iz;
    const float j11 = fy * iz, j12 = -fy * yc * iz * iz;
    float P0[3], P1[3];
    #pragma unroll
    for (int c = 0; c < 3; ++c) {
        P0[c] = j00*V[0][c] + j02*V[2][c];
        P1[c] = j11*V[1][c] + j12*V[2][c];
    }
    const float a = P0[0]*j00 + P0[2]*j02;
    const float b = P0[1]*j11 + P0[2]*j12;
    const float c = P1[1]*j11 + P1[2]*j12;

    const float lam_max = 0.5f*(a + c) + sqrtf(fmaxf(0.25f*(a - c)*(a - c) + b*b, 0.0f));
    const float radius = 3.0f * sqrtf(fmaxf(lam_max, 0.0f));

    const bool visible = (zc > NEAR_P) && (zc < FAR_P) &&
                         (px >= 0.0f) && (px < (float)IMG_W) &&
                         (py >= 0.0f) && (py < (float)IMG_H);

    const float eps = 1e-6f;
    const float ae = a + eps, ce = c + eps;
    const float det = ae*ce - b*b;
    const float idet = fast_rcp(det);

    g.px = px; g.py = py;
    g.ia = ce * idet; g.ib = -b * idet; g.ic = ae * idet;
    g.op = opac[i];
    g.cr = colors[3*i+0]; g.cg = colors[3*i+1]; g.cb = colors[3*i+2];
    g.z = zc;
    const float cxp = floorf(px), cyp = floorf(py);
    const float r_int = floorf(radius) + 1.0f;
    g.xlo = cxp - r_int; g.xhi = cxp + r_int;
    g.ylo = cyp - r_int; g.yhi = cyp + r_int;
    g.vis = visible ? 1 : 0;
    g.radius = radius;
    return g;
}

// ---------------- fused: prep + tile-cull + stable compact + rank-sort + composite ----------------
// One block per 16x20 tile (240 blocks -> 1 per CU). 320 threads.
// Threads 0..255 prep 2 gaussians each; all 320 threads composite one pixel.
__global__ void __launch_bounds__(TPB)
fused_render_kernel(const float* __restrict__ means,
                    const float* __restrict__ scales,
                    const float* __restrict__ rots,
                    const float* __restrict__ colors,
                    const float* __restrict__ opac,
                    const float* __restrict__ Km,
                    const float* __restrict__ Tm,
                    float* __restrict__ out)
{
    // AoS: 4 float4 rows per sorted survivor:
    // row0 = {xlo,xhi,ylo,yhi}  row1 = {px,py,ia,ib}  row2 = {ic,op,z,cr}  row3 = {cg,cb,-,-}
    __shared__ float4 s_g[NG * 4 + 4];   // +4: box-prefetch overread pad
    __shared__ float  s_zkey[NG];
    __shared__ int    s_wsum[TPB / 64];

    const int tid  = threadIdx.x;
    const int lane = tid & 63;
    const int wid  = tid >> 6;

    const float fx = Km[0], fy = Km[4], cx = Km[2], cy = Km[5];
    const float Rc00 = Tm[0],  Rc01 = Tm[1],  Rc02 = Tm[2],  t0 = Tm[3];
    const float Rc10 = Tm[4],  Rc11 = Tm[5],  Rc12 = Tm[6],  t1 = Tm[7];
    const float Rc20 = Tm[8],  Rc21 = Tm[9],  Rc22 = Tm[10], t2 = Tm[11];

    const int tiles_x = IMG_W / TILE_W;             // 20
    const int tile_id = blockIdx.x;
    const int tx0 = (tile_id % tiles_x) * TILE_W;
    const int ty0 = (tile_id / tiles_x) * TILE_H;
    const float ftx0 = (float)tx0, ftx1 = (float)(tx0 + TILE_W - 1);
    const float fty0 = (float)ty0, fty1 = (float)(ty0 + TILE_H - 1);

    // --- prep 2 gaussians per thread (registers only); threads >=256 idle here ---
    GP p0, p1;
    int f0 = 0, f1 = 0;
    if (tid < 256) {
        const int g0 = 2 * tid, g1 = 2 * tid + 1;
        p0 = prep_gaussian(g0, means, scales, rots, colors, opac, fx, fy, cx, cy,
                           Rc00, Rc01, Rc02, t0, Rc10, Rc11, Rc12, t1, Rc20, Rc21, Rc22, t2);
        p1 = prep_gaussian(g1, means, scales, rots, colors, opac, fx, fy, cx, cy,
                           Rc00, Rc01, Rc02, t0, Rc10, Rc11, Rc12, t1, Rc20, Rc21, Rc22, t2);

        if (tile_id == 0) {
            float* radii_out = out + IMG_H*IMG_W*5;
            radii_out[g0] = p0.vis ? p0.radius : 0.0f;
            radii_out[g1] = p1.vis ? p1.radius : 0.0f;
        }

        // --- cull against tile ---
        f0 = p0.vis && (p0.xhi >= ftx0) && (p0.xlo <= ftx1) && (p0.yhi >= fty0) && (p0.ylo <= fty1);
        f1 = p1.vis && (p1.xhi >= ftx0) && (p1.xlo <= ftx1) && (p1.yhi >= fty0) && (p1.ylo <= fty1);
    }

    // --- stable prefix scan (wave shuffle + cross-wave offsets; wave 4 contributes 0) ---
    int c = f0 + f1;
    #pragma unroll
    for (int d = 1; d < 64; d <<= 1) {
        int n = __shfl_up(c, d);
        if (lane >= d) c += n;
    }
    if (lane == 63) s_wsum[wid] = c;
    __syncthreads();
    int woff = 0;
    #pragma unroll
    for (int w = 0; w < TPB / 64; ++w)
        woff += (w < wid) ? s_wsum[w] : 0;
    const int excl = woff + c - (f0 + f1);
    const int q0 = excl;          // compact position == original-index order rank
    const int q1 = excl + f0;
    int M = 0;
    #pragma unroll
    for (int w = 0; w < TPB / 64; ++w) M += s_wsum[w];

    // --- write z keys at compact positions ---
    if (f0) s_zkey[q0] = p0.z;
    if (f1) s_zkey[q1] = p1.z;
    __syncthreads();

    // --- rank among survivors (descending z, stable by compact position) and
    //     write full AoS row directly into the sorted slot ---
    if (f0) {
        const float key = p0.z;
        int r = 0;
        for (int j = 0; j < M; ++j) {
            const float kj = s_zkey[j];
            r += (kj > key) || (kj == key && j < q0);
        }
        s_g[4*r+0] = make_float4(p0.xlo, p0.xhi, p0.ylo, p0.yhi);
        s_g[4*r+1] = make_float4(p0.px,  p0.py,  p0.ia,  p0.ib);
        s_g[4*r+2] = make_float4(p0.ic,  p0.op,  p0.z,   p0.cr);
        s_g[4*r+3] = make_float4(p0.cg,  p0.cb,  0.0f,   0.0f);
    }
    if (f1) {
        const float key = p1.z;
        int r = 0;
        for (int j = 0; j < M; ++j) {
            const float kj = s_zkey[j];
            r += (kj > key) || (kj == key && j < q1);
        }
        s_g[4*r+0] = make_float4(p1.xlo, p1.xhi, p1.ylo, p1.yhi);
        s_g[4*r+1] = make_float4(p1.px,  p1.py,  p1.ia,  p1.ib);
        s_g[4*r+2] = make_float4(p1.ic,  p1.op,  p1.z,   p1.cr);
        s_g[4*r+3] = make_float4(p1.cg,  p1.cb,  0.0f,   0.0f);
    }
    __syncthreads();

    // --- composite: one thread per pixel, sorted compacted list, 1-deep box prefetch ---
    const int lx = tid & (TILE_W - 1);
    const int ly = tid >> 4;                  // 0..19
    const int xi = tx0 + lx;
    const int yi = ty0 + ly;
    const float gx = (float)xi;
    const float gy = (float)yi;

    float T = 1.0f;
    float accR = 0.0f, accG = 0.0f, accB = 0.0f, accA = 0.0f;
    float depth = 0.0f;
    bool has = false;

    float4 box = s_g[0];
    for (int i = 0; i < M; ++i) {
        const float4 boxn = s_g[4*i+4];   // prefetch next (pad makes i==M-1 safe)
        if (gx >= box.x && gx <= box.y && gy >= box.z && gy <= box.w) {
            const float4 r1 = s_g[4*i+1];
            const float4 r2 = s_g[4*i+2];
            const float4 r3 = s_g[4*i+3];
            const float dx = gx - r1.x;
            const float dy = gy - r1.y;
            const float mahal = r1.z*dx*dx + 2.0f*r1.w*dx*dy + r2.x*dy*dy;
            const float g = __expf(-0.5f * mahal);
            const float alpha = fminf(r2.y * g, 0.99f);   // op*g >= 0 always
            const float w = alpha * T;
            accR += w * r2.w;
            accG += w * r3.x;
            accB += w * r3.y;
            accA += w;
            if (!has && w > 0.01f) { depth = r2.z; has = true; }
            T *= (1.0f - alpha);
            // future contributions bounded by T: color/alpha error <= 1e-4,
            // and future w < 1e-4 < 0.01 can never set depth -> safe early out.
            if (T < 1e-4f) break;
        }
        box = boxn;
    }

    const int p = yi * IMG_W + xi;
    float* rendered  = out;                          // [H,W,3]
    float* depth_map = out + IMG_H*IMG_W*3;          // [H,W]
    float* alpha_map = out + IMG_H*IMG_W*4;          // [H,W]

    rendered[3*p+0] = fminf(fmaxf(accR, 0.0f), 1.0f);
    rendered[3*p+1] = fminf(fmaxf(accG, 0.0f), 1.0f);
    rendered[3*p+2] = fminf(fmaxf(accB, 0.0f), 1.0f);
    depth_map[p] = has ? depth : 0.0f;
    alpha_map[p] = fminf(fmaxf(accA, 0.0f), 1.0f);
}

extern "C" void kernel_launch(void* const* d_in, const int* in_sizes, int n_in,
                              void* d_out, int out_size, void* d_ws, size_t ws_size,
                              hipStream_t stream) {
    const float* means  = (const float*)d_in[0];
    const float* scales = (const float*)d_in[1];
    const float* rots   = (const float*)d_in[2];
    const float* colors = (const float*)d_in[3];
    const float* opac   = (const float*)d_in[4];
    const float* Km     = (const float*)d_in[5];
    const float* Tm     = (const float*)d_in[6];
    float* out = (float*)d_out;
    (void)d_ws; (void)ws_size; (void)in_sizes; (void)n_in; (void)out_size;

    const int ntiles = (IMG_W / TILE_W) * (IMG_H / TILE_H);   // 20*12 = 240
    hipLaunchKernelGGL(fused_render_kernel, dim3(ntiles), dim3(TPB), 0, stream,
                       means, scales, rots, colors, opac, Km, Tm, out);
}